// Round 1
// baseline (1554.289 us; speedup 1.0000x reference)
//
#include <hip/hip_runtime.h>

// YuaTopKRouter: logits = H[32768,4096] @ W[64,4096]^T ; top-2 ; softmax over the 2.
// Outputs (concat, fp32): topk_weight [32768,2] then topk_idx [32768,2] (stored as floats).
//
// Strategy (fp32 baseline):
//  - 512 blocks x 256 threads; block owns 64 tokens; 4 waves split K (1024 each).
//  - lane -> token. Per k, the 64 expert weights are wave-uniform -> scalar loads
//    (s_load) from a K-major transposed copy of W in d_ws; FMA density ~97%.
//  - H staged global->regs (float4 coalesced) -> LDS transposed (+1 pad), register
//    prefetch of next chunk overlapped with compute. No __syncthreads in main loop
//    (each wave owns a private LDS region; DS ops are in-order per wave).
//  - Cross-wave reduce via LDS, then wave 0 does top-2 scan + softmax + store.

#define NT 32768
#define ND 4096
#define NE 64
#define BT 64
#define KC 64
#define NWAVE 4
#define KSLICE (ND / NWAVE)   // 1024
#define NCHUNK (KSLICE / KC)  // 16

__global__ void transpose_w_kernel(const float* __restrict__ W, float* __restrict__ Wt) {
    int i = blockIdx.x * 256 + threadIdx.x;   // i over ND*NE
    int e = i & (NE - 1);
    int k = i >> 6;
    Wt[i] = W[e * ND + k];                    // Wt[k*64 + e] = W[e][k]
}

template <int WSTRIDE>
__global__ __launch_bounds__(256, 2) void router_kernel(
    const float* __restrict__ H, const float* __restrict__ Wsrc, float* __restrict__ out)
{
    // Staging: lds[w][k][t] (64 x 65 floats per wave). Reused as reduce area lds[w][t][e].
    __shared__ float lds[NWAVE][KC][BT + 1];
    const int tid  = threadIdx.x;
    const int wave = tid >> 6;
    const int lane = tid & 63;
    const int t0   = blockIdx.x * BT;
    const int kw0  = wave * KSLICE;
    const int st   = lane >> 4;   // sub-token 0..3 within a load instr
    const int kq   = lane & 15;   // k-quad index

    float acc[NE];
#pragma unroll
    for (int e = 0; e < NE; ++e) acc[e] = 0.0f;

    float* wlds = &lds[wave][0][0];

    // Register prefetch of chunk 0: lane loads float4 of H[t0+g*4+st][kw0 + kq*4 .. +3]
    float4 pre[16];
    const float* hb = H + (size_t)t0 * ND + kw0 + kq * 4;
#pragma unroll
    for (int g = 0; g < 16; ++g)
        pre[g] = *reinterpret_cast<const float4*>(hb + (size_t)(g * 4 + st) * ND);

    for (int c = 0; c < NCHUNK; ++c) {
        // Write staged chunk to LDS transposed: (t, kl) -> wlds[kl*(BT+1) + t]
        // Bank pattern: 2-way conflicts only (free on CDNA4).
#pragma unroll
        for (int g = 0; g < 16; ++g) {
            const int t  = g * 4 + st;
            const int kl = kq * 4;
            wlds[(kl + 0) * (BT + 1) + t] = pre[g].x;
            wlds[(kl + 1) * (BT + 1) + t] = pre[g].y;
            wlds[(kl + 2) * (BT + 1) + t] = pre[g].z;
            wlds[(kl + 3) * (BT + 1) + t] = pre[g].w;
        }
        // Prefetch next chunk while computing this one.
        if (c + 1 < NCHUNK) {
#pragma unroll
            for (int g = 0; g < 16; ++g)
                pre[g] = *reinterpret_cast<const float4*>(
                    hb + (size_t)(g * 4 + st) * ND + (c + 1) * KC);
        }

        const int kg0 = kw0 + c * KC;
        for (int k = 0; k < KC; ++k) {
            // h for MY token at this k: consecutive lanes -> consecutive addrs, conflict-free.
            const float h = wlds[k * (BT + 1) + lane];
            // Wave-uniform weight row -> scalar loads.
            const float* __restrict__ wrow =
                (WSTRIDE == 1) ? (Wsrc + (size_t)(kg0 + k) * NE) : (Wsrc + (kg0 + k));
#pragma unroll
            for (int e = 0; e < NE; ++e)
                acc[e] = fmaf(h, wrow[(size_t)e * WSTRIDE], acc[e]);
        }
    }

    // Each wave writes its partial logits to its own region: lds[w][t][e], pad keeps
    // both writes (lane-major) and later reads conflict-free.
#pragma unroll
    for (int e = 0; e < NE; ++e) lds[wave][lane][e] = acc[e];
    __syncthreads();

    if (wave == 0) {
        // lane == token within block. Sum 4 partials per expert, online top-2 scan.
        float m1 = -3.0e38f, m2 = -3.0e38f;
        int   i1 = 0, i2 = 0;
        for (int e = 0; e < NE; ++e) {
            const float v = lds[0][lane][e] + lds[1][lane][e] +
                            lds[2][lane][e] + lds[3][lane][e];
            if (v > m1) { m2 = m1; i2 = i1; m1 = v; i1 = e; }
            else if (v > m2) { m2 = v; i2 = e; }
        }
        // softmax over [m1, m2], m1 >= m2 so ex <= 1 (no overflow).
        const float ex = __expf(m2 - m1);
        const float w1 = 1.0f / (1.0f + ex);
        const int   t  = t0 + lane;
        out[(size_t)t * 2 + 0] = w1;
        out[(size_t)t * 2 + 1] = ex * w1;
        float* oi = out + (size_t)NT * 2;   // indices chunk, stored as float values
        oi[(size_t)t * 2 + 0] = (float)i1;
        oi[(size_t)t * 2 + 1] = (float)i2;
    }
}

extern "C" void kernel_launch(void* const* d_in, const int* in_sizes, int n_in,
                              void* d_out, int out_size, void* d_ws, size_t ws_size,
                              hipStream_t stream) {
    const float* H = (const float*)d_in[0];
    const float* W = (const float*)d_in[1];
    float* out = (float*)d_out;

    const size_t wt_bytes = (size_t)ND * NE * sizeof(float);
    if (ws_size >= wt_bytes) {
        float* Wt = (float*)d_ws;
        // d_ws is re-poisoned before every call -> recompute the transpose each time.
        transpose_w_kernel<<<(ND * NE) / 256, 256, 0, stream>>>(W, Wt);
        router_kernel<1><<<NT / BT, 256, 0, stream>>>(H, Wt, out);
    } else {
        // Fallback: read W in its native [e][k] layout (still wave-uniform scalar loads).
        router_kernel<ND><<<NT / BT, 256, 0, stream>>>(H, W, out);
    }
}